// Round 5
// baseline (735.745 us; speedup 1.0000x reference)
//
#include <hip/hip_runtime.h>

// ---------------- constants ----------------
#define BATCH 2
#define SEQ   2048
#define HID   2048
#define NH    16
#define DN    128
#define DR    64
#define DV    128
#define RANK  512
#define DQK   192            // DN + DR
#define NQ    (NH*DQK)       // 3072
#define NKVA  576            // RANK + DR
#define NKVAP 640            // padded to /128
#define NKVB  (NH*(DN+DV))   // 4096
#define NTOK  (BATCH*SEQ)    // 4096
#define SCALE_F 0.07216878364870323f  // 192^-0.5

typedef __bf16 bf16x8 __attribute__((ext_vector_type(8)));
typedef float  f32x4  __attribute__((ext_vector_type(4)));
typedef unsigned int u32x4 __attribute__((ext_vector_type(4)));
typedef unsigned short u16;
typedef unsigned short u16x4 __attribute__((ext_vector_type(4)));

__device__ __forceinline__ float b2f(u16 h) {
    unsigned int u = ((unsigned int)h) << 16;
    float f; __builtin_memcpy(&f, &u, 4); return f;
}
__device__ __forceinline__ u16 f2b(float f) {
    unsigned int x; __builtin_memcpy(&x, &f, 4);
    unsigned int r = x + 0x7fffu + ((x >> 16) & 1u);
    return (u16)(r >> 16);
}
__device__ __forceinline__ bf16x8 lds_frag(const u16* p) {
    u32x4 v = *(const u32x4*)p;
    return __builtin_bit_cast(bf16x8, v);
}
__device__ __forceinline__ bf16x8 to_frag(u32x4 v) {
    return __builtin_bit_cast(bf16x8, v);
}
__device__ __forceinline__ f32x4 mfma16(bf16x8 a, bf16x8 b, f32x4 c) {
    return __builtin_amdgcn_mfma_f32_16x16x32_bf16(a, b, c, 0, 0, 0);
}
__device__ __forceinline__ void store_out(u16* p, float v) { *p = f2b(v); }
__device__ __forceinline__ void store_out(float* p, float v) { *p = v; }
// async global->LDS, 16B per lane; LDS addrs must be wave-contiguous (base + lane*16)
__device__ __forceinline__ void gld_lds16(const u16* g, u16* l) {
    __builtin_amdgcn_global_load_lds(
        (const __attribute__((address_space(1))) unsigned int*)g,
        (__attribute__((address_space(3))) unsigned int*)l, 16, 0, 0);
}

// ---------------- fp32 -> bf16 cast (hidden_states) ----------------
__global__ void cast_f32_bf16(const float* __restrict__ in, u16* __restrict__ out, int n4) {
    int i = blockIdx.x * blockDim.x + threadIdx.x;
    if (i >= n4) return;
    f32x4 v = *(const f32x4*)(in + (size_t)i * 4);
    u16 o[4];
    for (int k = 0; k < 4; k++) o[k] = f2b(v[k]);
    *(unsigned long long*)(out + (size_t)i * 4) = *(unsigned long long*)o;
}

// ---------------- weight transpose+cast, 64x64 tile, vectorized both sides ----------
// in: R x C row-major fp32.  out: Cp x R row-major bf16; tiles with c0>=C are zeros.
__global__ void transpose_pad(const float* __restrict__ in, u16* __restrict__ out,
                              int R, int C, int Cp) {
    __shared__ unsigned int t32[64 * 65];
    int r0 = blockIdx.x * 64, c0 = blockIdx.y * 64;
    int tid = threadIdx.x;
    bool valid = (c0 < C);
    for (int i = 0; i < 4; i++) {
        int u = tid + i * 256;
        int rl = u >> 4, c4 = u & 15;       // 64 rows x 16 float4-chunks
        f32x4 v = {0.f, 0.f, 0.f, 0.f};
        if (valid) v = *(const f32x4*)&in[(size_t)(r0 + rl) * C + c0 + c4 * 4];
        for (int j = 0; j < 4; j++)
            t32[(c4 * 4 + j) * 65 + rl] = f2b(v[j]);   // t32[c][r], 2-way-free banking
    }
    __syncthreads();
    for (int i = 0; i < 2; i++) {
        int u = tid + i * 256;
        int cl = u >> 3, r8 = (u & 7) * 8;  // 64 cols x 8 chunks of 8 rows
        unsigned int w[8];
        for (int j = 0; j < 8; j++) w[j] = t32[cl * 65 + r8 + j];
        u32x4 pk;
        for (int j = 0; j < 4; j++) pk[j] = (w[2 * j] & 0xffffu) | (w[2 * j + 1] << 16);
        *(u32x4*)&out[(size_t)(c0 + cl) * R + r0 + r8] = pk;
    }
}

// ---------------- generic bf16 GEMM: C[M,N] = A[M,K] * Bt[N,K]^T ----------------
// 128x128 tile, BK=32, 256 threads, async global->LDS staging (m97 pattern).
template <typename OutT>
__global__ __launch_bounds__(256) void gemm_bt(const u16* __restrict__ A,
                                               const u16* __restrict__ Bt,
                                               OutT* __restrict__ C,
                                               int K, int lda, int ldb, int ldc) {
    __shared__ u16 As[128 * 32];
    __shared__ u16 Bs[128 * 32];
    int tid = threadIdx.x, lane = tid & 63, w = tid >> 6;
    int wm = (w >> 1) * 64, wn = (w & 1) * 64;
    int g = lane >> 4, ln = lane & 15;
    int m0 = blockIdx.y * 128, n0 = blockIdx.x * 128;
    f32x4 acc[4][4] = {};
    for (int k0 = 0; k0 < K; k0 += 32) {
        for (int i = 0; i < 2; i++) {
            int ch = tid + i * 256;          // 0..511 = 128 rows x 4 chunks(16B)
            int row = ch >> 2, o = ch & 3;
            gld_lds16(&A[(size_t)(m0 + row) * lda + k0 + o * 8], &As[row * 32 + o * 8]);
            gld_lds16(&Bt[(size_t)(n0 + row) * ldb + k0 + o * 8], &Bs[row * 32 + o * 8]);
        }
        __syncthreads();
        bf16x8 af[4], bf[4];
        for (int i = 0; i < 4; i++) af[i] = lds_frag(&As[(wm + i * 16 + ln) * 32 + g * 8]);
        for (int j = 0; j < 4; j++) bf[j] = lds_frag(&Bs[(wn + j * 16 + ln) * 32 + g * 8]);
        for (int i = 0; i < 4; i++)
            for (int j = 0; j < 4; j++)
                acc[i][j] = mfma16(af[i], bf[j], acc[i][j]);
        __syncthreads();
    }
    for (int i = 0; i < 4; i++)
        for (int j = 0; j < 4; j++)
            for (int r = 0; r < 4; r++) {
                int m = m0 + wm + i * 16 + g * 4 + r;
                int n = n0 + wn + j * 16 + ln;
                store_out(&C[(size_t)m * ldc + n], acc[i][j][r]);
            }
}

// ---------------- RoPE on q (in-place, last 64 of each head's 192) ----------------
__global__ void rope_q(u16* __restrict__ q, const float* __restrict__ freqs) {
    int token = blockIdx.x;
    int s = token & (SEQ - 1);
    int tid = threadIdx.x;
    for (int i = 0; i < 2; i++) {
        int idx = tid + i * 256;          // 512 pairs = 16 heads * 32
        int hh = idx >> 5, p = idx & 31;
        float th = freqs[s * 32 + p];
        float c = __cosf(th), sn = __sinf(th);
        size_t off = (size_t)token * NQ + hh * DQK + DN + 2 * p;
        float x1 = b2f(q[off]), x2 = b2f(q[off + 1]);
        q[off]     = f2b(x1 * c - x2 * sn);
        q[off + 1] = f2b(x1 * sn + x2 * c);
    }
}

// ---------------- LayerNorm over RANK=512 cols of kvraw (ld 640) ----------------
__global__ void ln_kv(const u16* __restrict__ kvraw, const float* __restrict__ gamma,
                      const float* __restrict__ beta, u16* __restrict__ kv_c) {
    int row = blockIdx.x, tid = threadIdx.x;
    size_t base = (size_t)row * NKVAP;
    float x0 = b2f(kvraw[base + tid]), x1 = b2f(kvraw[base + 256 + tid]);
    float s = x0 + x1, q2 = x0 * x0 + x1 * x1;
    for (int o = 32; o > 0; o >>= 1) { s += __shfl_xor(s, o); q2 += __shfl_xor(q2, o); }
    __shared__ float sh[8];
    int lane = tid & 63, w = tid >> 6;
    if (lane == 0) { sh[w] = s; sh[4 + w] = q2; }
    __syncthreads();
    float S = sh[0] + sh[1] + sh[2] + sh[3];
    float Q2 = sh[4] + sh[5] + sh[6] + sh[7];
    float mu = S * (1.f / 512.f);
    float var = Q2 * (1.f / 512.f) - mu * mu;
    float rs = rsqrtf(var + 1e-5f);
    kv_c[(size_t)row * RANK + tid] =
        f2b((x0 - mu) * rs * gamma[tid] + beta[tid]);
    kv_c[(size_t)row * RANK + 256 + tid] =
        f2b((x1 - mu) * rs * gamma[256 + tid] + beta[256 + tid]);
}

// ---------------- assemble K_full(b,s,h,192) = [k_nope | rope(k_rope)] ----------------
__global__ void k_assemble(const u16* __restrict__ kvb, const u16* __restrict__ kvraw,
                           const float* __restrict__ freqs, u16* __restrict__ Kf) {
    int token = blockIdx.x;
    int s = token & (SEQ - 1);
    int tid = threadIdx.x;
    __shared__ u16 roped[64];
    if (tid < 32) {
        int p = tid;
        float th = freqs[s * 32 + p];
        float c = __cosf(th), sn = __sinf(th);
        float x1 = b2f(kvraw[(size_t)token * NKVAP + RANK + 2 * p]);
        float x2 = b2f(kvraw[(size_t)token * NKVAP + RANK + 2 * p + 1]);
        roped[2 * p]     = f2b(x1 * c - x2 * sn);
        roped[2 * p + 1] = f2b(x1 * sn + x2 * c);
    }
    __syncthreads();
    {   // k_nope: 16 heads x 128 = 256 chunks of 8 u16 (16B)
        int hh = tid >> 4, d8 = (tid & 15) * 8;
        *(u32x4*)&Kf[(size_t)token * NQ + hh * DQK + d8] =
            *(const u32x4*)&kvb[(size_t)token * NKVB + hh * 256 + d8];
    }
    if (tid < 128) {  // rope broadcast: 16 heads x 64 = 128 chunks of 8
        int hh = tid >> 3, d8 = (tid & 7) * 8;
        *(u32x4*)&Kf[(size_t)token * NQ + hh * DQK + DN + d8] = *(u32x4*)&roped[d8];
    }
}

// ---------------- V transpose: Vt[b,h,d,s] from kvb[b,s,h,128+d], 64x64 tiles ------
__global__ void v_transpose(const u16* __restrict__ kvb, u16* __restrict__ Vt) {
    __shared__ unsigned int t32[64 * 65];
    int st = blockIdx.x * 64, dt = blockIdx.y * 64;
    int b = blockIdx.z >> 4, h = blockIdx.z & 15;
    int tid = threadIdx.x;
    for (int i = 0; i < 2; i++) {
        int u = tid + i * 256;
        int sl = u >> 3, c8 = (u & 7) * 8;   // 64 s-rows x 8 chunks of 8 d
        u32x4 v = *(const u32x4*)&kvb[((size_t)(b * SEQ + st + sl) * NH + h) * 256 + DN + dt + c8];
        for (int j = 0; j < 4; j++) {
            t32[(c8 + 2 * j) * 65 + sl]     = v[j] & 0xffffu;
            t32[(c8 + 2 * j + 1) * 65 + sl] = v[j] >> 16;
        }
    }
    __syncthreads();
    for (int i = 0; i < 2; i++) {
        int u = tid + i * 256;
        int dl = u >> 3, s8 = (u & 7) * 8;   // 64 d-rows x 8 chunks of 8 s
        unsigned int w[8];
        for (int j = 0; j < 8; j++) w[j] = t32[dl * 65 + s8 + j];
        u32x4 pk;
        for (int j = 0; j < 4; j++) pk[j] = (w[2 * j] & 0xffffu) | (w[2 * j + 1] << 16);
        *(u32x4*)&Vt[((size_t)(b * NH + h) * DV + dt + dl) * SEQ + st + s8] = pk;
    }
}

// ---------------- flash attention v4: async-K (chunk-major LDS), V from global,
// ---------------- 4 blocks/CU (grid 1024 == resident slots, zero tail) ----------
// grid (S/64, NH, B); 64 q rows per block, 64 kv per iter, 4 waves.
#define KC    64
#define QTILE 64
#define PSTR  72
#define NIT  (SEQ / KC)
__global__ __launch_bounds__(256, 4) void attn_kernel(const u16* __restrict__ Q,
                                                      const u16* __restrict__ Kf,
                                                      const u16* __restrict__ Vt,
                                                      u16* __restrict__ O) {
    // Ks chunk-major: [chunk j 0..23][row r 0..63] x 8 u16 (16B granules).
    // DMA-linear (lds addr = lane*16) AND frag reads at the 8-dw/bank floor.
    __shared__ u16 Ks[24 * 64 * 8];     // 24.6 KB
    __shared__ u16 Ps[QTILE * PSTR];    // 9.2 KB   P[q][kv]
    __shared__ float lsumLDS[2][QTILE]; // 0.5 KB   (total 34.3 KB -> 4 blocks/CU)
    int tid = threadIdx.x, lane = tid & 63, w = tid >> 6;
    int w1 = w & 1;    // q 32-half
    int w2 = w >> 1;   // kv 32-half (QK) / d 64-half (PV)
    int g = lane >> 4, ln = lane & 15;
    int qt = blockIdx.x, h = blockIdx.y, b = blockIdx.z;

    size_t qbase  = ((size_t)(b * SEQ + qt * QTILE) * NH + h) * DQK;
    size_t kbase0 = ((size_t)(b * SEQ) * NH + h) * DQK;
    size_t vbase  = (size_t)(b * NH + h) * DV * SEQ;

    // Q fragments -> registers (loop-invariant B-operand; 12 x bf16x8 = 48 VGPR)
    bf16x8 bfq[2][6];
    for (int ni = 0; ni < 2; ni++)
        for (int kk = 0; kk < 6; kk++)
            bfq[ni][kk] = to_frag(*(const u32x4*)&Q[qbase +
                (size_t)(w1 * 32 + ni * 16 + ln) * NQ + kk * 32 + g * 8]);

    f32x4 oacc[2][4] = {};
    float lpriv[2] = {0.f, 0.f};

    for (int kt = 0; kt < NIT; kt++) {
        // async-stage K(kt): LDS linear in lane; global chunk (r = c&63, j = c>>6)
        size_t kb = kbase0 + (size_t)kt * KC * NQ;
        for (int i = 0; i < 6; i++) {
            int c = tid + i * 256;
            int r = c & 63, j = c >> 6;
            gld_lds16(&Kf[kb + (size_t)r * NQ + j * 8], &Ks[c * 8]);
        }
        __syncthreads();   // vmcnt(0) drain -> Ks ready

        // S^T[kv][q] = K . Q^T  (C rows = kv, so P packs along kv)
        f32x4 sacc[2][2] = {};
        for (int kk = 0; kk < 6; kk++) {
            bf16x8 af[2];
            for (int mi = 0; mi < 2; mi++)
                af[mi] = lds_frag(&Ks[(((kk * 4 + g) << 6) + w2 * 32 + mi * 16 + ln) * 8]);
            for (int mi = 0; mi < 2; mi++)
                for (int ni = 0; ni < 2; ni++)
                    sacc[mi][ni] = mfma16(af[mi], bfq[ni][kk], sacc[mi][ni]);
        }
        // exp + private row-sum + packed b64 P store
        for (int mi = 0; mi < 2; mi++)
            for (int ni = 0; ni < 2; ni++) {
                float p0 = __expf(sacc[mi][ni][0] * SCALE_F);
                float p1 = __expf(sacc[mi][ni][1] * SCALE_F);
                float p2 = __expf(sacc[mi][ni][2] * SCALE_F);
                float p3 = __expf(sacc[mi][ni][3] * SCALE_F);
                lpriv[ni] += (p0 + p1) + (p2 + p3);
                u16x4 pk = { f2b(p0), f2b(p1), f2b(p2), f2b(p3) };
                *(u16x4*)&Ps[(w1 * 32 + ni * 16 + ln) * PSTR + (w2 * 32 + mi * 16 + g * 4)] = pk;
            }
        // V fragments for this tile straight from global (L2-hot); latency hidden
        // behind the barrier + Ps reads + other resident waves.
        u32x4 vb[2][4];
        {
            int c0 = kt * KC;
            for (int kk = 0; kk < 2; kk++)
                for (int ni = 0; ni < 4; ni++)
                    vb[kk][ni] = *(const u32x4*)&Vt[vbase +
                        (size_t)(w2 * 64 + ni * 16 + ln) * SEQ + c0 + kk * 32 + g * 8];
        }
        __syncthreads();   // Ps visible (also separates Ks reads from next stage)

        // O[q][d] += P . V
        for (int kk = 0; kk < 2; kk++) {
            bf16x8 pa[2];
            for (int mi = 0; mi < 2; mi++)
                pa[mi] = lds_frag(&Ps[(w1 * 32 + mi * 16 + ln) * PSTR + kk * 32 + g * 8]);
            for (int mi = 0; mi < 2; mi++)
                for (int ni = 0; ni < 4; ni++)
                    oacc[mi][ni] = mfma16(pa[mi], to_frag(vb[kk][ni]), oacc[mi][ni]);
        }
    }

    // final lsum reduction (once per kernel)
    for (int ni = 0; ni < 2; ni++) {
        float v = lpriv[ni];
        v += __shfl_xor(v, 16);
        v += __shfl_xor(v, 32);
        if (g == 0) lsumLDS[w2][w1 * 32 + ni * 16 + ln] = v;
    }
    __syncthreads();
    for (int mi = 0; mi < 2; mi++)
        for (int ni = 0; ni < 4; ni++) {
            int d = w2 * 64 + ni * 16 + ln;
            for (int r = 0; r < 4; r++) {
                int row = w1 * 32 + mi * 16 + g * 4 + r;
                float l = lsumLDS[0][row] + lsumLDS[1][row];
                O[((size_t)(b * SEQ + qt * QTILE + row) * NH + h) * DV + d] =
                    f2b(oacc[mi][ni][r] / l);
            }
        }
}

// ---------------- launcher ----------------
extern "C" void kernel_launch(void* const* d_in, const int* in_sizes, int n_in,
                              void* d_out, int out_size, void* d_ws, size_t ws_size,
                              hipStream_t stream) {
    const float* hs_f  = (const float*)d_in[0];
    const float* freqs = (const float*)d_in[1];
    const float* Wq    = (const float*)d_in[2];
    const float* Wkva  = (const float*)d_in[3];
    const float* gamma = (const float*)d_in[4];
    const float* beta  = (const float*)d_in[5];
    const float* Wkvb  = (const float*)d_in[6];
    const float* Wout  = (const float*)d_in[7];
    float* outp = (float*)d_out;

    char* ws = (char*)d_ws;
    size_t off = 0;
    auto alloc = [&](size_t elems) -> u16* {
        u16* p = (u16*)(ws + off);
        off += ((elems * 2 + 255) / 256) * 256;
        return p;
    };
    u16* hs    = alloc((size_t)NTOK * HID);
    u16* WqT   = alloc((size_t)NQ * HID);
    u16* WkvaT = alloc((size_t)NKVAP * HID);
    u16* WkvbT = alloc((size_t)NKVB * RANK);
    u16* WoutT = alloc((size_t)HID * HID);
    u16* q_raw = alloc((size_t)NTOK * NQ);
    u16* kvraw = alloc((size_t)NTOK * NKVAP);
    u16* kv_c  = alloc((size_t)NTOK * RANK);
    u16* kvb   = alloc((size_t)NTOK * NKVB);
    u16* Kf    = alloc((size_t)NTOK * NQ);
    u16* Vt    = alloc((size_t)BATCH * NH * DV * SEQ);
    u16* attn  = alloc((size_t)NTOK * NH * DV);
    (void)ws_size; (void)in_sizes; (void)n_in; (void)out_size;

    cast_f32_bf16<<<(NTOK * HID / 4 + 255) / 256, 256, 0, stream>>>(hs_f, hs, NTOK * HID / 4);
    transpose_pad<<<dim3(HID / 64, NQ / 64), 256, 0, stream>>>(Wq, WqT, HID, NQ, NQ);
    transpose_pad<<<dim3(HID / 64, NKVAP / 64), 256, 0, stream>>>(Wkva, WkvaT, HID, NKVA, NKVAP);
    transpose_pad<<<dim3(RANK / 64, NKVB / 64), 256, 0, stream>>>(Wkvb, WkvbT, RANK, NKVB, NKVB);
    transpose_pad<<<dim3(HID / 64, HID / 64), 256, 0, stream>>>(Wout, WoutT, HID, HID, HID);

    gemm_bt<<<dim3(NQ / 128, NTOK / 128), 256, 0, stream>>>(hs, WqT, q_raw, HID, HID, HID, NQ);
    rope_q<<<NTOK, 256, 0, stream>>>(q_raw, freqs);

    gemm_bt<<<dim3(NKVAP / 128, NTOK / 128), 256, 0, stream>>>(hs, WkvaT, kvraw, HID, HID, HID, NKVAP);
    ln_kv<<<NTOK, 256, 0, stream>>>(kvraw, gamma, beta, kv_c);

    gemm_bt<<<dim3(NKVB / 128, NTOK / 128), 256, 0, stream>>>(kv_c, WkvbT, kvb, RANK, RANK, RANK, NKVB);

    k_assemble<<<NTOK, 256, 0, stream>>>(kvb, kvraw, freqs, Kf);
    v_transpose<<<dim3(SEQ / 64, DV / 64, BATCH * NH), 256, 0, stream>>>(kvb, Vt);

    attn_kernel<<<dim3(SEQ / QTILE, NH, BATCH), 256, 0, stream>>>(q_raw, Kf, Vt, attn);

    gemm_bt<<<dim3(HID / 128, NTOK / 128), 256, 0, stream>>>(attn, WoutT, outp, HID, HID, HID, HID);
}

// Round 7
// 481.197 us; speedup vs baseline: 1.5290x; 1.5290x over previous
//
#include <hip/hip_runtime.h>

// ---------------- constants ----------------
#define BATCH 2
#define SEQ   2048
#define HID   2048
#define NH    16
#define DN    128
#define DR    64
#define DV    128
#define RANK  512
#define DQK   192            // DN + DR
#define NQ    (NH*DQK)       // 3072
#define NQKV  3712           // NQ + 640 (kv_a padded)
#define NKVB  (NH*(DN+DV))   // 4096
#define NTOK  (BATCH*SEQ)    // 4096
#define SCALE_F 0.07216878364870323f  // 192^-0.5

typedef __bf16 bf16x8 __attribute__((ext_vector_type(8)));
typedef float  f32x4  __attribute__((ext_vector_type(4)));
typedef unsigned int u32x4 __attribute__((ext_vector_type(4)));
typedef unsigned short u16;
typedef unsigned short u16x4 __attribute__((ext_vector_type(4)));

__device__ __forceinline__ float b2f(u16 h) {
    unsigned int u = ((unsigned int)h) << 16;
    float f; __builtin_memcpy(&f, &u, 4); return f;
}
__device__ __forceinline__ u16 f2b(float f) {
    unsigned int x; __builtin_memcpy(&x, &f, 4);
    unsigned int r = x + 0x7fffu + ((x >> 16) & 1u);
    return (u16)(r >> 16);
}
__device__ __forceinline__ bf16x8 lds_frag(const u16* p) {
    u32x4 v = *(const u32x4*)p;
    return __builtin_bit_cast(bf16x8, v);
}
__device__ __forceinline__ bf16x8 to_frag(u32x4 v) {
    return __builtin_bit_cast(bf16x8, v);
}
__device__ __forceinline__ f32x4 mfma16(bf16x8 a, bf16x8 b, f32x4 c) {
    return __builtin_amdgcn_mfma_f32_16x16x32_bf16(a, b, c, 0, 0, 0);
}
__device__ __forceinline__ void store_out(u16* p, float v) { *p = f2b(v); }
__device__ __forceinline__ void store_out(float* p, float v) { *p = v; }
__device__ __forceinline__ void gld_lds16(const u16* g, u16* l) {
    __builtin_amdgcn_global_load_lds(
        (const __attribute__((address_space(1))) unsigned int*)g,
        (__attribute__((address_space(3))) unsigned int*)l, 16, 0, 0);
}

// ---------------- fused prep: hs cast + 4 weight transposes, one launch ----------
__global__ __launch_bounds__(256) void prep_kernel(
        const float* __restrict__ hs_f, u16* __restrict__ hs,
        const float* __restrict__ Wq, const float* __restrict__ Wkva,
        const float* __restrict__ Wkvb, const float* __restrict__ Wout,
        u16* __restrict__ WqkvT, u16* __restrict__ WkvbT, u16* __restrict__ WoutT) {
    int tid = threadIdx.x;
    int bid = blockIdx.x;
    if (bid < 8192) {            // cast: 8192*256 f32x4 = NTOK*HID elems
        int i = bid * 256 + tid;
        f32x4 v = *(const f32x4*)(hs_f + (size_t)i * 4);
        u16 o[4];
        for (int k = 0; k < 4; k++) o[k] = f2b(v[k]);
        *(unsigned long long*)(hs + (size_t)i * 4) = *(unsigned long long*)o;
        return;
    }
    bid -= 8192;
    const float* in; u16* out; int R, C, tilesC;
    if (bid < 1536)      { in = Wq;   out = WqkvT;                       R = HID;  C = NQ;   tilesC = 48; }
    else if (bid < 1856) { bid -= 1536; in = Wkva; out = WqkvT + (size_t)NQ * HID; R = HID; C = 576; tilesC = 10; }
    else if (bid < 2368) { bid -= 1856; in = Wkvb; out = WkvbT;          R = RANK; C = NKVB; tilesC = 64; }
    else                 { bid -= 2368; in = Wout; out = WoutT;          R = HID;  C = HID;  tilesC = 32; }
    __shared__ unsigned int t32[64 * 65];
    int r0 = (bid / tilesC) * 64, c0 = (bid % tilesC) * 64;
    bool valid = (c0 < C);
    for (int i = 0; i < 4; i++) {
        int u = tid + i * 256;
        int rl = u >> 4, c4 = u & 15;
        f32x4 v = {0.f, 0.f, 0.f, 0.f};
        if (valid) v = *(const f32x4*)&in[(size_t)(r0 + rl) * C + c0 + c4 * 4];
        for (int j = 0; j < 4; j++)
            t32[(c4 * 4 + j) * 65 + rl] = f2b(v[j]);
    }
    __syncthreads();
    for (int i = 0; i < 2; i++) {
        int u = tid + i * 256;
        int cl = u >> 3, r8 = (u & 7) * 8;
        unsigned int w[8];
        for (int j = 0; j < 8; j++) w[j] = t32[cl * 65 + r8 + j];
        u32x4 pk;
        for (int j = 0; j < 4; j++) pk[j] = (w[2 * j] & 0xffffu) | (w[2 * j + 1] << 16);
        *(u32x4*)&out[(size_t)(c0 + cl) * R + r0 + r8] = pk;
    }
}

// ---------------- generic bf16 GEMM: C[M,N] = A[M,K] * Bt[N,K]^T (m97 pattern) ----
template <typename OutT>
__global__ __launch_bounds__(256) void gemm_bt(const u16* __restrict__ A,
                                               const u16* __restrict__ Bt,
                                               OutT* __restrict__ C,
                                               int K, int lda, int ldb, int ldc) {
    __shared__ u16 As[128 * 32];
    __shared__ u16 Bs[128 * 32];
    int tid = threadIdx.x, lane = tid & 63, w = tid >> 6;
    int wm = (w >> 1) * 64, wn = (w & 1) * 64;
    int g = lane >> 4, ln = lane & 15;
    int m0 = blockIdx.y * 128, n0 = blockIdx.x * 128;
    f32x4 acc[4][4] = {};
    for (int k0 = 0; k0 < K; k0 += 32) {
        for (int i = 0; i < 2; i++) {
            int ch = tid + i * 256;
            int row = ch >> 2, o = ch & 3;
            gld_lds16(&A[(size_t)(m0 + row) * lda + k0 + o * 8], &As[row * 32 + o * 8]);
            gld_lds16(&Bt[(size_t)(n0 + row) * ldb + k0 + o * 8], &Bs[row * 32 + o * 8]);
        }
        __syncthreads();
        bf16x8 af[4], bf[4];
        for (int i = 0; i < 4; i++) af[i] = lds_frag(&As[(wm + i * 16 + ln) * 32 + g * 8]);
        for (int j = 0; j < 4; j++) bf[j] = lds_frag(&Bs[(wn + j * 16 + ln) * 32 + g * 8]);
        for (int i = 0; i < 4; i++)
            for (int j = 0; j < 4; j++)
                acc[i][j] = mfma16(af[i], bf[j], acc[i][j]);
        __syncthreads();
    }
    for (int i = 0; i < 4; i++)
        for (int j = 0; j < 4; j++)
            for (int r = 0; r < 4; r++) {
                int m = m0 + wm + i * 16 + g * 4 + r;
                int n = n0 + wn + j * 16 + ln;
                store_out(&C[(size_t)m * ldc + n], acc[i][j][r]);
            }
}

// ---------------- RoPE on q (in-place on qkv, last 64 of each head's 192) --------
__global__ void rope_q(u16* __restrict__ qkv, const float* __restrict__ freqs) {
    int token = blockIdx.x;
    int s = token & (SEQ - 1);
    int tid = threadIdx.x;
    for (int i = 0; i < 2; i++) {
        int idx = tid + i * 256;          // 512 pairs = 16 heads * 32
        int hh = idx >> 5, p = idx & 31;
        float th = freqs[s * 32 + p];
        float c = __cosf(th), sn = __sinf(th);
        size_t off = (size_t)token * NQKV + hh * DQK + DN + 2 * p;
        float x1 = b2f(qkv[off]), x2 = b2f(qkv[off + 1]);
        qkv[off]     = f2b(x1 * c - x2 * sn);
        qkv[off + 1] = f2b(x1 * sn + x2 * c);
    }
}

// ---------------- LayerNorm over RANK cols of qkv (cols NQ..NQ+511) --------------
__global__ void ln_kv(const u16* __restrict__ qkv, const float* __restrict__ gamma,
                      const float* __restrict__ beta, u16* __restrict__ kv_c) {
    int row = blockIdx.x, tid = threadIdx.x;
    size_t base = (size_t)row * NQKV + NQ;
    float x0 = b2f(qkv[base + tid]), x1 = b2f(qkv[base + 256 + tid]);
    float s = x0 + x1, q2 = x0 * x0 + x1 * x1;
    for (int o = 32; o > 0; o >>= 1) { s += __shfl_xor(s, o); q2 += __shfl_xor(q2, o); }
    __shared__ float sh[8];
    int lane = tid & 63, w = tid >> 6;
    if (lane == 0) { sh[w] = s; sh[4 + w] = q2; }
    __syncthreads();
    float S = sh[0] + sh[1] + sh[2] + sh[3];
    float Q2 = sh[4] + sh[5] + sh[6] + sh[7];
    float mu = S * (1.f / 512.f);
    float var = Q2 * (1.f / 512.f) - mu * mu;
    float rs = rsqrtf(var + 1e-5f);
    kv_c[(size_t)row * RANK + tid] =
        f2b((x0 - mu) * rs * gamma[tid] + beta[tid]);
    kv_c[(size_t)row * RANK + 256 + tid] =
        f2b((x1 - mu) * rs * gamma[256 + tid] + beta[256 + tid]);
}

// ---------------- assemble K_full(b,s,h,192) = [k_nope | rope(k_rope)] ------------
__global__ void k_assemble(const u16* __restrict__ kvb, const u16* __restrict__ qkv,
                           const float* __restrict__ freqs, u16* __restrict__ Kf) {
    int token = blockIdx.x;
    int s = token & (SEQ - 1);
    int tid = threadIdx.x;
    __shared__ u16 roped[64];
    if (tid < 32) {
        int p = tid;
        float th = freqs[s * 32 + p];
        float c = __cosf(th), sn = __sinf(th);
        float x1 = b2f(qkv[(size_t)token * NQKV + NQ + RANK + 2 * p]);
        float x2 = b2f(qkv[(size_t)token * NQKV + NQ + RANK + 2 * p + 1]);
        roped[2 * p]     = f2b(x1 * c - x2 * sn);
        roped[2 * p + 1] = f2b(x1 * sn + x2 * c);
    }
    __syncthreads();
    {   // k_nope: 16 heads x 128 = 256 chunks of 8 u16 (16B)
        int hh = tid >> 4, d8 = (tid & 15) * 8;
        *(u32x4*)&Kf[(size_t)token * NQ + hh * DQK + d8] =
            *(const u32x4*)&kvb[(size_t)token * NKVB + hh * 256 + d8];
    }
    if (tid < 128) {  // rope broadcast: 16 heads x 64 = 128 chunks of 8
        int hh = tid >> 3, d8 = (tid & 7) * 8;
        *(u32x4*)&Kf[(size_t)token * NQ + hh * DQK + DN + d8] = *(u32x4*)&roped[d8];
    }
}

// ---------------- V transpose: Vt[b,h,d,s] from kvb[b,s,h,128+d], 64x64 tiles ------
__global__ void v_transpose(const u16* __restrict__ kvb, u16* __restrict__ Vt) {
    __shared__ unsigned int t32[64 * 65];
    int st = blockIdx.x * 64, dt = blockIdx.y * 64;
    int b = blockIdx.z >> 4, h = blockIdx.z & 15;
    int tid = threadIdx.x;
    for (int i = 0; i < 2; i++) {
        int u = tid + i * 256;
        int sl = u >> 3, c8 = (u & 7) * 8;
        u32x4 v = *(const u32x4*)&kvb[((size_t)(b * SEQ + st + sl) * NH + h) * 256 + DN + dt + c8];
        for (int j = 0; j < 4; j++) {
            t32[(c8 + 2 * j) * 65 + sl]     = v[j] & 0xffffu;
            t32[(c8 + 2 * j + 1) * 65 + sl] = v[j] >> 16;
        }
    }
    __syncthreads();
    for (int i = 0; i < 2; i++) {
        int u = tid + i * 256;
        int dl = u >> 3, s8 = (u & 7) * 8;
        unsigned int w[8];
        for (int j = 0; j < 8; j++) w[j] = t32[dl * 65 + s8 + j];
        u32x4 pk;
        for (int j = 0; j < 4; j++) pk[j] = (w[2 * j] & 0xffffu) | (w[2 * j + 1] << 16);
        *(u32x4*)&Vt[((size_t)(b * NH + h) * DV + dt + dl) * SEQ + st + s8] = pk;
    }
}

// ---------------- flash attention: round-4-validated kernel (Q stride = NQKV) -----
#define KC    64
#define QTILE 64
#define QSTR 200   // 192 data + 8 pad
#define PSTR 72
#define VSTR 72
#define NIT  (SEQ / KC)
__global__ __launch_bounds__(256, 3) void attn_kernel(const u16* __restrict__ Q,
                                                      const u16* __restrict__ Kf,
                                                      const u16* __restrict__ Vt,
                                                      u16* __restrict__ O) {
    __shared__ u16 Ks[KC * QSTR];       // 25.6 KB
    __shared__ u16 Ps[QTILE * PSTR];    // 9.2 KB   P[q][kv]
    __shared__ u16 Vs[DV * VSTR];       // 18.4 KB  V^T[d][kv]
    __shared__ float lsumLDS[2][QTILE]; // 0.5 KB   (53.76 KB -> 3 blocks/CU)
    int tid = threadIdx.x, lane = tid & 63, w = tid >> 6;
    int w1 = w & 1;    // q 32-half
    int w2 = w >> 1;   // kv 32-half (QK) / d 64-half (PV)
    int g = lane >> 4, ln = lane & 15;
    int qt = blockIdx.x, h = blockIdx.y, b = blockIdx.z;

    size_t qbase  = ((size_t)(b * SEQ + qt * QTILE)) * NQKV + h * DQK;
    size_t kbase0 = ((size_t)(b * SEQ) * NH + h) * DQK;
    size_t vbase  = (size_t)(b * NH + h) * DV * SEQ;

    // Q fragments -> registers (pre-roped in memory by rope_q)
    bf16x8 bfq[2][6];
    for (int ni = 0; ni < 2; ni++)
        for (int kk = 0; kk < 6; kk++)
            bfq[ni][kk] = to_frag(*(const u32x4*)&Q[qbase +
                (size_t)(w1 * 32 + ni * 16 + ln) * NQKV + kk * 32 + g * 8]);

    // prefetch tile 0 into regs
    u32x4 kpre[6], vpre[4];
    {
        int krow = tid >> 2;
        for (int i = 0; i < 6; i++) {
            int o = (tid & 3) + 4 * i;
            kpre[i] = *(const u32x4*)&Kf[kbase0 + (size_t)krow * NQ + o * 8];
        }
        int vrow = tid >> 1;
        for (int i = 0; i < 4; i++) {
            int o = (tid & 1) + 2 * i;
            vpre[i] = *(const u32x4*)&Vt[vbase + (size_t)vrow * SEQ + o * 8];
        }
    }
    f32x4 oacc[2][4] = {};
    float lpriv[2] = {0.f, 0.f};

    for (int kt = 0; kt < NIT; kt++) {
        // stage prefetched K/V tile
        {
            int krow = tid >> 2;
            for (int i = 0; i < 6; i++) {
                int o = (tid & 3) + 4 * i;
                *(u32x4*)&Ks[krow * QSTR + o * 8] = kpre[i];
            }
            int vrow = tid >> 1;
            for (int i = 0; i < 4; i++) {
                int o = (tid & 1) + 2 * i;
                *(u32x4*)&Vs[vrow * VSTR + o * 8] = vpre[i];
            }
        }
        __syncthreads();
        // issue next prefetch (overlaps with QK + softmax + PV)
        if (kt + 1 < NIT) {
            size_t kb = kbase0 + (size_t)(kt + 1) * KC * NQ;
            int krow = tid >> 2;
            for (int i = 0; i < 6; i++) {
                int o = (tid & 3) + 4 * i;
                kpre[i] = *(const u32x4*)&Kf[kb + (size_t)krow * NQ + o * 8];
            }
            int vrow = tid >> 1;
            int c0 = (kt + 1) * KC;
            for (int i = 0; i < 4; i++) {
                int o = (tid & 1) + 2 * i;
                vpre[i] = *(const u32x4*)&Vt[vbase + (size_t)vrow * SEQ + c0 + o * 8];
            }
        }
        // S^T[kv][q] = K . Q^T
        f32x4 sacc[2][2] = {};
        for (int kk = 0; kk < 6; kk++) {
            bf16x8 af[2];
            for (int mi = 0; mi < 2; mi++)
                af[mi] = lds_frag(&Ks[(w2 * 32 + mi * 16 + ln) * QSTR + kk * 32 + g * 8]);
            for (int mi = 0; mi < 2; mi++)
                for (int ni = 0; ni < 2; ni++)
                    sacc[mi][ni] = mfma16(af[mi], bfq[ni][kk], sacc[mi][ni]);
        }
        // exp + private row-sum + packed b64 P store
        for (int mi = 0; mi < 2; mi++)
            for (int ni = 0; ni < 2; ni++) {
                float p0 = __expf(sacc[mi][ni][0] * SCALE_F);
                float p1 = __expf(sacc[mi][ni][1] * SCALE_F);
                float p2 = __expf(sacc[mi][ni][2] * SCALE_F);
                float p3 = __expf(sacc[mi][ni][3] * SCALE_F);
                lpriv[ni] += (p0 + p1) + (p2 + p3);
                u16x4 pk = { f2b(p0), f2b(p1), f2b(p2), f2b(p3) };
                *(u16x4*)&Ps[(w1 * 32 + ni * 16 + ln) * PSTR + (w2 * 32 + mi * 16 + g * 4)] = pk;
            }
        __syncthreads();
        // O[q][d] += P . V
        for (int kk = 0; kk < 2; kk++) {
            bf16x8 pa[2], vb[4];
            for (int mi = 0; mi < 2; mi++)
                pa[mi] = lds_frag(&Ps[(w1 * 32 + mi * 16 + ln) * PSTR + kk * 32 + g * 8]);
            for (int ni = 0; ni < 4; ni++)
                vb[ni] = lds_frag(&Vs[(w2 * 64 + ni * 16 + ln) * VSTR + kk * 32 + g * 8]);
            for (int mi = 0; mi < 2; mi++)
                for (int ni = 0; ni < 4; ni++)
                    oacc[mi][ni] = mfma16(pa[mi], vb[ni], oacc[mi][ni]);
        }
        __syncthreads();
    }

    // final lsum reduction
    for (int ni = 0; ni < 2; ni++) {
        float v = lpriv[ni];
        v += __shfl_xor(v, 16);
        v += __shfl_xor(v, 32);
        if (g == 0) lsumLDS[w2][w1 * 32 + ni * 16 + ln] = v;
    }
    __syncthreads();
    for (int mi = 0; mi < 2; mi++)
        for (int ni = 0; ni < 4; ni++) {
            int d = w2 * 64 + ni * 16 + ln;
            for (int r = 0; r < 4; r++) {
                int row = w1 * 32 + mi * 16 + g * 4 + r;
                float l = lsumLDS[0][row] + lsumLDS[1][row];
                O[((size_t)(b * SEQ + qt * QTILE + row) * NH + h) * DV + d] =
                    f2b(oacc[mi][ni][r] / l);
            }
        }
}

// ---------------- launcher ----------------
extern "C" void kernel_launch(void* const* d_in, const int* in_sizes, int n_in,
                              void* d_out, int out_size, void* d_ws, size_t ws_size,
                              hipStream_t stream) {
    const float* hs_f  = (const float*)d_in[0];
    const float* freqs = (const float*)d_in[1];
    const float* Wq    = (const float*)d_in[2];
    const float* Wkva  = (const float*)d_in[3];
    const float* gamma = (const float*)d_in[4];
    const float* beta  = (const float*)d_in[5];
    const float* Wkvb  = (const float*)d_in[6];
    const float* Wout  = (const float*)d_in[7];
    float* outp = (float*)d_out;

    char* ws = (char*)d_ws;
    size_t off = 0;
    auto alloc = [&](size_t elems) -> u16* {
        u16* p = (u16*)(ws + off);
        off += ((elems * 2 + 255) / 256) * 256;
        return p;
    };
    u16* hs     = alloc((size_t)NTOK * HID);
    u16* WqkvT  = alloc((size_t)NQKV * HID);     // rows 0..3071 Wq^T, 3072..3711 Wkva^T (padded)
    u16* WkvbT  = alloc((size_t)NKVB * RANK);
    u16* WoutT  = alloc((size_t)HID * HID);
    u16* qkv    = alloc((size_t)NTOK * NQKV);    // q | kv_a output
    u16* kv_c   = alloc((size_t)NTOK * RANK);
    u16* kvb    = alloc((size_t)NTOK * NKVB);
    u16* Kf     = alloc((size_t)NTOK * NQ);
    u16* Vt     = alloc((size_t)BATCH * NH * DV * SEQ);
    u16* attn   = alloc((size_t)NTOK * NH * DV);
    (void)ws_size; (void)in_sizes; (void)n_in; (void)out_size;

    // 1. fused prep: cast + all weight transposes
    prep_kernel<<<8192 + 1536 + 320 + 512 + 1024, 256, 0, stream>>>(
        hs_f, hs, Wq, Wkva, Wkvb, Wout, WqkvT, WkvbT, WoutT);

    // 2. fused q + kv_a GEMM: (4096 x 3712 x 2048)
    gemm_bt<<<dim3(NQKV / 128, NTOK / 128), 256, 0, stream>>>(hs, WqkvT, qkv, HID, HID, HID, NQKV);

    // 3. RoPE on q (in place)
    rope_q<<<NTOK, 256, 0, stream>>>(qkv, freqs);

    // 4. layernorm
    ln_kv<<<NTOK, 256, 0, stream>>>(qkv, gamma, beta, kv_c);

    // 5. kvb = kv_c @ Wkv_b (4096 x 4096 x 512)
    gemm_bt<<<dim3(NKVB / 128, NTOK / 128), 256, 0, stream>>>(kv_c, WkvbT, kvb, RANK, RANK, RANK, NKVB);

    // 6. K assembly
    k_assemble<<<NTOK, 256, 0, stream>>>(kvb, qkv, freqs, Kf);

    // 7. V transpose
    v_transpose<<<dim3(SEQ / 64, DV / 64, BATCH * NH), 256, 0, stream>>>(kvb, Vt);

    // 8. attention (round-4 kernel)
    attn_kernel<<<dim3(SEQ / QTILE, NH, BATCH), 256, 0, stream>>>(qkv, Kf, Vt, attn);

    // 9. out = attn @ Wout (4096 x 2048 x 2048)
    gemm_bt<<<dim3(HID / 128, NTOK / 128), 256, 0, stream>>>(attn, WoutT, outp, HID, HID, HID, HID);
}